// Round 13
// baseline (826.453 us; speedup 1.0000x reference)
//
#include <hip/hip_runtime.h>

typedef _Float16 f16;
typedef _Float16 f16x4 __attribute__((ext_vector_type(4)));
typedef _Float16 f16x8 __attribute__((ext_vector_type(8)));
typedef float f32x4 __attribute__((ext_vector_type(4)));

#define LRELU(v) ((v) >= 0.f ? (v) : 0.01f * (v))

__device__ __forceinline__ int swz(int a) { return a ^ (((a >> 7) & 7) << 4); }

__device__ __forceinline__ f16x4 shflx4(f16x4 v, int m) {
  union { f16x4 h; int i[2]; } u;
  u.h = v;
  u.i[0] = __shfl_xor(u.i[0], m);
  u.i[1] = __shfl_xor(u.i[1], m);
  return u.h;
}

#define TILE 4096

// ---------------- setup: feat_small + weight prep + coarse hist (trailing blocks) ----------------
__global__ __launch_bounds__(256) void setup_kernel(
    const float* __restrict__ num_prop, const float* __restrict__ cat_prop,
    const float* __restrict__ W_num, const float* __restrict__ b_num,
    const float* __restrict__ W_cat, const float* __restrict__ b_cat,
    const float* __restrict__ W_des, const float* __restrict__ W_in,
    const float* __restrict__ W_root, const float* __restrict__ W_rel,
    const float* __restrict__ W_o1,
    f16* __restrict__ x0,
    f16* __restrict__ WtDes, f16* __restrict__ WtIn, f16* __restrict__ WtR,
    f16* __restrict__ WtO1,
    const int* __restrict__ ei, int* __restrict__ hist,
    int N, int nbf, int E, int NB)
{
  __shared__ int h[512];
  int b = blockIdx.x;
  int tid = threadIdx.x;
  if (b < nbf) {
    int w = (b * 256 + tid) >> 6;
    int lane = tid & 63;
    if (w < N) {
      const float* npr = num_prop + (size_t)w * 4;
      const float* cpr = cat_prop + (size_t)w * 3;
      float vn = b_num[lane];
#pragma unroll
      for (int k = 0; k < 4; k++) vn += npr[k] * W_num[k * 64 + lane];
      float vc = b_cat[lane];
#pragma unroll
      for (int k = 0; k < 3; k++) vc += cpr[k] * W_cat[k * 64 + lane];
      vn = LRELU(vn);
      vc = LRELU(vc);
      x0[(size_t)w * 192 + 64 + lane] = (f16)vn;
      x0[(size_t)w * 192 + 128 + lane] = (f16)vc;
    }
    return;
  }
  b -= nbf;
  if (b < 192) {
    int idx = b * 256 + tid;
    if (idx < 64 * 768) { int n = idx / 768, k = idx % 768; WtDes[idx] = (f16)W_des[k * 64 + n]; }
    return;
  }
  b -= 192;
  if (b < 144) {
    int idx = b * 256 + tid;
    if (idx < 192 * 192) { int n = idx / 192, k = idx % 192; WtIn[idx] = (f16)W_in[k * 192 + n]; }
    return;
  }
  b -= 144;
  if (b < 432) {
    int idx = b * 256 + tid;
    if (idx < 192 * 576) {
      int n = idx / 576, k = idx % 576;
      int seg = k / 192, kk = k % 192;
      float v = (seg == 0) ? W_root[kk * 192 + n] : W_rel[(seg - 1) * 192 * 192 + kk * 192 + n];
      WtR[idx] = (f16)v;
    }
    return;
  }
  b -= 432;
  if (b < 144) {
    int idx = b * 256 + tid;
    if (idx < 192 * 192) { int n = idx / 192, k = idx % 192; WtO1[idx] = (f16)W_o1[k * 192 + n]; }
    return;
  }
  b -= 144;
  for (int i = tid; i < NB; i += 256) h[i] = 0;
  __syncthreads();
  const int base = b * TILE;
#pragma unroll
  for (int i = 0; i < TILE / 256; ++i) {
    int e = base + i * 256 + tid;
    if (e < E) atomicAdd(&h[ei[E + e] >> 8], 1);
  }
  __syncthreads();
  for (int i = tid; i < NB; i += 256) hist[b * NB + i] = h[i];
}

// ---------------- bin scan + per-(tile,bin) exclusive bases (in place) ----------------
__global__ __launch_bounds__(512) void scan_kernel(
    int* __restrict__ hist, int* __restrict__ binbase, int NB, int NBLK)
{
  __shared__ int s[512];
  const int b = threadIdx.x;
  int total = 0;
  if (b < NB) {
#pragma unroll 8
    for (int blk = 0; blk < NBLK; ++blk) total += hist[blk * NB + b];
  }
  s[b] = total;
  __syncthreads();
  for (int off = 1; off < 512; off <<= 1) {
    int v = (b >= off) ? s[b - off] : 0;
    __syncthreads();
    s[b] += v;
    __syncthreads();
  }
  int ex = (b == 0) ? 0 : s[b - 1];
  if (b < NB) binbase[b] = ex;
  if (b == 0) binbase[NB] = s[511];
  if (b < NB) {
    int run = ex;
#pragma unroll 8
    for (int blk = 0; blk < NBLK; ++blk) {
      int t = hist[blk * NB + b];
      hist[blk * NB + b] = run;
      run += t;
    }
  }
}

// ---------------- DIAGNOSTIC: des-GEMM with K-loop x REP, scratch output ----------------
// Duration ~= REP x (des-GEMM time). Output not validated; deterministic.
__global__ __launch_bounds__(256) void diag_des_kernel(
    const float* __restrict__ A, const f16* __restrict__ Bt,
    const float* __restrict__ bias, f16* __restrict__ Cscr, int M)
{
  __shared__ f16 lA[128 * 64];
  __shared__ f16 lB[64 * 64];
  const int tid = threadIdx.x;
  const int lane = tid & 63, wid = tid >> 6;
  const int wm = wid >> 1, wn = wid & 1;
  const int m0 = blockIdx.x * 128;
  f32x4 acc[4][2] = {};
  const int arow = tid >> 3;
  const int acolf = (tid & 7) * 8;
  const float* aptr[4];
#pragma unroll
  for (int p = 0; p < 4; ++p) {
    int gr = m0 + p * 32 + arow;
    if (gr >= M) gr = M - 1;
    aptr[p] = A + (size_t)gr * 768 + acolf;
  }
  float4 pa[4][2];
  f16x8 pb[2];
  auto load_chunk = [&](int k0) {
#pragma unroll
    for (int p = 0; p < 4; ++p) {
      const float4* s = reinterpret_cast<const float4*>(aptr[p] + k0);
      pa[p][0] = s[0];
      pa[p][1] = s[1];
    }
#pragma unroll
    for (int i = 0; i < 2; ++i) {
      int c = tid + i * 256;
      int n = c >> 3, k8 = c & 7;
      pb[i] = *reinterpret_cast<const f16x8*>(Bt + (size_t)n * 768 + k0 + k8 * 8);
    }
  };
  for (int rep = 0; rep < 2; ++rep) {
    load_chunk(0);
    for (int k0 = 0; k0 < 768; k0 += 64) {
#pragma unroll
      for (int p = 0; p < 4; ++p) {
        f16x8 h;
        h[0] = (f16)pa[p][0].x; h[1] = (f16)pa[p][0].y; h[2] = (f16)pa[p][0].z; h[3] = (f16)pa[p][0].w;
        h[4] = (f16)pa[p][1].x; h[5] = (f16)pa[p][1].y; h[6] = (f16)pa[p][1].z; h[7] = (f16)pa[p][1].w;
        int row = p * 32 + arow;
        *reinterpret_cast<f16x8*>((char*)lA + swz(row * 128 + (tid & 7) * 16)) = h;
      }
#pragma unroll
      for (int i = 0; i < 2; ++i) {
        int c = tid + i * 256;
        int n = c >> 3, k8 = c & 7;
        *reinterpret_cast<f16x8*>((char*)lB + swz(n * 128 + k8 * 16)) = pb[i];
      }
      if (k0 + 64 < 768) load_chunk(k0 + 64);
      __syncthreads();
#pragma unroll
      for (int ks = 0; ks < 2; ks++) {
        f16x8 af[4], bf[2];
#pragma unroll
        for (int fm = 0; fm < 4; fm++) {
          int row = wm * 64 + fm * 16 + (lane & 15);
          af[fm] = *reinterpret_cast<const f16x8*>((const char*)lA + swz(row * 128 + ks * 64 + (lane >> 4) * 16));
        }
#pragma unroll
        for (int fn = 0; fn < 2; fn++) {
          int nn = wn * 32 + fn * 16 + (lane & 15);
          bf[fn] = *reinterpret_cast<const f16x8*>((const char*)lB + swz(nn * 128 + ks * 64 + (lane >> 4) * 16));
        }
#pragma unroll
        for (int fm = 0; fm < 4; fm++)
#pragma unroll
          for (int fn = 0; fn < 2; fn++)
            acc[fm][fn] = __builtin_amdgcn_mfma_f32_16x16x32_f16(af[fm], bf[fn], acc[fm][fn], 0, 0, 0);
      }
      __syncthreads();
    }
  }
#pragma unroll
  for (int fm = 0; fm < 4; fm++) {
#pragma unroll
    for (int fn = 0; fn < 2; fn++) {
      int gc = wn * 32 + fn * 16 + (lane & 15);
      float b = bias[gc];
#pragma unroll
      for (int r = 0; r < 4; r++) {
        int gr = m0 + wm * 64 + fm * 16 + (lane >> 4) * 4 + r;
        if (gr < M) {
          float v = acc[fm][fn][r] + b;
          Cscr[(size_t)gr * 64 + gc] = (f16)LRELU(v);
        }
      }
    }
  }
}

// ---------------- merged des-GEMM (pipelined reg-prefetch staging) + bin scatter ----------------
__global__ __launch_bounds__(256) void scatterdes_kernel(
    const float* __restrict__ A, const f16* __restrict__ Bt,
    const float* __restrict__ bias, f16* __restrict__ C, int M,
    const int* __restrict__ ei, const int* __restrict__ et,
    const int* __restrict__ hist, int* __restrict__ sorted,
    int E, int NB, int nbDES)
{
  __shared__ f16 lA[128 * 64];
  __shared__ f16 lB[64 * 64];
  const int tid = threadIdx.x;
  if ((int)blockIdx.x >= nbDES) {
    int blk = (int)blockIdx.x - nbDES;
    int* cur = (int*)lA;
    for (int i = tid; i < NB; i += 256) cur[i] = hist[blk * NB + i];
    __syncthreads();
    const int base = blk * TILE;
#pragma unroll
    for (int i = 0; i < TILE / 256; ++i) {
      int e = base + i * 256 + tid;
      if (e < E) {
        int src = ei[e];
        int dst = ei[E + e];
        int r = et[e];
        int slot = atomicAdd(&cur[dst >> 8], 1);
        sorted[slot] = src | (r << 17) | ((dst & 255) << 18);
      }
    }
    return;
  }
  const int lane = tid & 63, wid = tid >> 6;
  const int wm = wid >> 1, wn = wid & 1;
  const int m0 = blockIdx.x * 128;
  f32x4 acc[4][2] = {};
  const int arow = tid >> 3;
  const int acolf = (tid & 7) * 8;
  const float* aptr[4];
#pragma unroll
  for (int p = 0; p < 4; ++p) {
    int gr = m0 + p * 32 + arow;
    if (gr >= M) gr = M - 1;
    aptr[p] = A + (size_t)gr * 768 + acolf;
  }
  float4 pa[4][2];
  f16x8 pb[2];
  auto load_chunk = [&](int k0) {
#pragma unroll
    for (int p = 0; p < 4; ++p) {
      const float4* s = reinterpret_cast<const float4*>(aptr[p] + k0);
      pa[p][0] = s[0];
      pa[p][1] = s[1];
    }
#pragma unroll
    for (int i = 0; i < 2; ++i) {
      int c = tid + i * 256;
      int n = c >> 3, k8 = c & 7;
      pb[i] = *reinterpret_cast<const f16x8*>(Bt + (size_t)n * 768 + k0 + k8 * 8);
    }
  };
  load_chunk(0);
  for (int k0 = 0; k0 < 768; k0 += 64) {
#pragma unroll
    for (int p = 0; p < 4; ++p) {
      f16x8 h;
      h[0] = (f16)pa[p][0].x; h[1] = (f16)pa[p][0].y; h[2] = (f16)pa[p][0].z; h[3] = (f16)pa[p][0].w;
      h[4] = (f16)pa[p][1].x; h[5] = (f16)pa[p][1].y; h[6] = (f16)pa[p][1].z; h[7] = (f16)pa[p][1].w;
      int row = p * 32 + arow;
      *reinterpret_cast<f16x8*>((char*)lA + swz(row * 128 + (tid & 7) * 16)) = h;
    }
#pragma unroll
    for (int i = 0; i < 2; ++i) {
      int c = tid + i * 256;
      int n = c >> 3, k8 = c & 7;
      *reinterpret_cast<f16x8*>((char*)lB + swz(n * 128 + k8 * 16)) = pb[i];
    }
    if (k0 + 64 < 768) load_chunk(k0 + 64);
    __syncthreads();
#pragma unroll
    for (int ks = 0; ks < 2; ks++) {
      f16x8 af[4], bf[2];
#pragma unroll
      for (int fm = 0; fm < 4; fm++) {
        int row = wm * 64 + fm * 16 + (lane & 15);
        af[fm] = *reinterpret_cast<const f16x8*>((const char*)lA + swz(row * 128 + ks * 64 + (lane >> 4) * 16));
      }
#pragma unroll
      for (int fn = 0; fn < 2; fn++) {
        int nn = wn * 32 + fn * 16 + (lane & 15);
        bf[fn] = *reinterpret_cast<const f16x8*>((const char*)lB + swz(nn * 128 + ks * 64 + (lane >> 4) * 16));
      }
#pragma unroll
      for (int fm = 0; fm < 4; fm++)
#pragma unroll
        for (int fn = 0; fn < 2; fn++)
          acc[fm][fn] = __builtin_amdgcn_mfma_f32_16x16x32_f16(af[fm], bf[fn], acc[fm][fn], 0, 0, 0);
    }
    __syncthreads();
  }
#pragma unroll
  for (int fm = 0; fm < 4; fm++) {
#pragma unroll
    for (int fn = 0; fn < 2; fn++) {
      int gc = wn * 32 + fn * 16 + (lane & 15);
      float b = bias[gc];
#pragma unroll
      for (int r = 0; r < 4; r++) {
        int gr = m0 + wm * 64 + fm * 16 + (lane >> 4) * 4 + r;
        if (gr < M) {
          float v = acc[fm][fn][r] + b;
          C[(size_t)gr * 192 + gc] = (f16)LRELU(v);
        }
      }
    }
  }
}

// ---------------- generic x-GEMM, pipelined reg-prefetch (+ optional CSR build blocks) ----------------
template <int NSEG, bool RELU, bool OUT2, bool BUILD>
__global__ __launch_bounds__(512) void gemm_x_kernel(
    const f16* __restrict__ A0, const f16* __restrict__ A1, const f16* __restrict__ A2,
    const f16* __restrict__ Bt, const float* __restrict__ bias,
    f16* __restrict__ C, int M,
    const float* __restrict__ W_o2, const float* __restrict__ b_o2,
    float* __restrict__ out,
    const int* __restrict__ sorted, const int* __restrict__ binbase,
    int* __restrict__ csr, int* __restrict__ rowptr, int nbGEMM)
{
  __shared__ f16 lA[128 * 64];
  __shared__ f16 lB[192 * 64];
  const int tid = threadIdx.x;
  if (BUILD && (int)blockIdx.x >= nbGEMM) {
    int bb = (int)blockIdx.x - nbGEMM;
    int* dcount = (int*)lA;
    int* lbase  = dcount + 256;
    int* cur    = lbase + 256;
    if (tid < 256) { dcount[tid] = 0; cur[tid] = 0; }
    __syncthreads();
    int start = binbase[bb], end = binbase[bb + 1];
    for (int j = start + tid; j < end; j += 512)
      atomicAdd(&dcount[(sorted[j] >> 18) & 255], 1);
    __syncthreads();
    if (tid < 256) lbase[tid] = dcount[tid];
    __syncthreads();
    for (int off = 1; off < 256; off <<= 1) {
      int v = 0;
      if (tid < 256 && tid >= off) v = lbase[tid - off];
      __syncthreads();
      if (tid < 256) lbase[tid] += v;
      __syncthreads();
    }
    if (tid < 256) {
      int dst = (bb << 8) + tid;
      if (dst < M) rowptr[dst] = start + lbase[tid] - dcount[tid];
    }
    __syncthreads();
    for (int j = start + tid; j < end; j += 512) {
      int it = sorted[j];
      int dl = (it >> 18) & 255;
      int pos = atomicAdd(&cur[dl], 1);
      int exb = start + lbase[dl] - dcount[dl];
      csr[exb + pos] = (it & 0x1FFFF) | (int)(((unsigned)((it >> 17) & 1)) << 31);
    }
    return;
  }
  const int lane = tid & 63, wid = tid >> 6;
  const int wm = wid >> 2, wn = wid & 3;
  const int m0 = blockIdx.x * 128;
  const int Ktot = NSEG * 192;
  const int NIT = NSEG * 3;
  f32x4 acc[4][3] = {};
  const f16* segs[3] = {A0, A1, A2};
  const int arow = tid >> 2, aq = tid & 3;
  int agr = m0 + arow;
  if (agr >= M) agr = M - 1;
  f16x8 pa0, pa1, pb[3];
  auto load_it = [&](int it) {
    const f16x8* s8 = reinterpret_cast<const f16x8*>(segs[it / 3] + (size_t)agr * 192 + (it % 3) * 64 + aq * 16);
    pa0 = s8[0];
    pa1 = s8[1];
#pragma unroll
    for (int i = 0; i < 3; i++) {
      int c = tid + i * 512;
      int n = c >> 3, k8 = c & 7;
      pb[i] = *reinterpret_cast<const f16x8*>(Bt + (size_t)n * Ktot + it * 64 + k8 * 8);
    }
  };
  load_it(0);
  for (int it = 0; it < NIT; it++) {
    {
      int b0 = arow * 128 + aq * 32;
      *reinterpret_cast<f16x8*>((char*)lA + swz(b0)) = pa0;
      *reinterpret_cast<f16x8*>((char*)lA + swz(b0 + 16)) = pa1;
#pragma unroll
      for (int i = 0; i < 3; i++) {
        int c = tid + i * 512;
        int n = c >> 3, k8 = c & 7;
        *reinterpret_cast<f16x8*>((char*)lB + swz(n * 128 + k8 * 16)) = pb[i];
      }
    }
    if (it + 1 < NIT) load_it(it + 1);
    __syncthreads();
#pragma unroll
    for (int ks = 0; ks < 2; ks++) {
      f16x8 af[4], bf[3];
#pragma unroll
      for (int fm = 0; fm < 4; fm++) {
        int row = wm * 64 + fm * 16 + (lane & 15);
        af[fm] = *reinterpret_cast<const f16x8*>((const char*)lA + swz(row * 128 + ks * 64 + (lane >> 4) * 16));
      }
#pragma unroll
      for (int fn = 0; fn < 3; fn++) {
        int nn = wn * 48 + fn * 16 + (lane & 15);
        bf[fn] = *reinterpret_cast<const f16x8*>((const char*)lB + swz(nn * 128 + ks * 64 + (lane >> 4) * 16));
      }
#pragma unroll
      for (int fm = 0; fm < 4; fm++)
#pragma unroll
        for (int fn = 0; fn < 3; fn++)
          acc[fm][fn] = __builtin_amdgcn_mfma_f32_16x16x32_f16(af[fm], bf[fn], acc[fm][fn], 0, 0, 0);
    }
    __syncthreads();
  }
  if (OUT2) {
    __shared__ float red[128][2];
    for (int i = tid; i < 256; i += 512) ((float*)red)[i] = 0.f;
    __syncthreads();
    float bb2[3], w2v[3][2];
#pragma unroll
    for (int fn = 0; fn < 3; fn++) {
      int gc = wn * 48 + fn * 16 + (lane & 15);
      bb2[fn] = bias[gc];
      w2v[fn][0] = W_o2[gc * 2 + 0];
      w2v[fn][1] = W_o2[gc * 2 + 1];
    }
#pragma unroll
    for (int fm = 0; fm < 4; fm++) {
#pragma unroll
      for (int r = 0; r < 4; r++) {
        float p0 = 0.f, p1 = 0.f;
#pragma unroll
        for (int fn = 0; fn < 3; fn++) {
          float v = acc[fm][fn][r] + bb2[fn];
          v = LRELU(v);
          p0 += v * w2v[fn][0];
          p1 += v * w2v[fn][1];
        }
#pragma unroll
        for (int m = 1; m < 16; m <<= 1) { p0 += __shfl_xor(p0, m); p1 += __shfl_xor(p1, m); }
        if ((lane & 15) == 0) {
          int lr = wm * 64 + fm * 16 + (lane >> 4) * 4 + r;
          atomicAdd(&red[lr][0], p0);
          atomicAdd(&red[lr][1], p1);
        }
      }
    }
    __syncthreads();
    if (tid < 256) {
      int gr = m0 + (tid >> 1);
      if (gr < M) out[(size_t)gr * 2 + (tid & 1)] = red[tid >> 1][tid & 1] + b_o2[tid & 1];
    }
  } else {
#pragma unroll
    for (int fm = 0; fm < 4; fm++) {
#pragma unroll
      for (int fn = 0; fn < 3; fn++) {
        int gc = wn * 48 + fn * 16 + (lane & 15);
        float b = bias[gc];
#pragma unroll
        for (int r = 0; r < 4; r++) {
          int gr = m0 + wm * 64 + fm * 16 + (lane >> 4) * 4 + r;
          if (gr < M) {
            float v = acc[fm][fn][r] + b;
            if (RELU) v = LRELU(v);
            C[(size_t)gr * 192 + gc] = (f16)v;
          }
        }
      }
    }
  }
}

// ---------------- CSR-based per-(dst,rel) mean aggregation v6 ----------------
__global__ __launch_bounds__(256) void agg_kernel(
    const f16* __restrict__ x, const int* __restrict__ csr,
    const int* __restrict__ rowptr,
    f16* __restrict__ agg0, f16* __restrict__ agg1, int N, int Etot)
{
  int w = (blockIdx.x << 2) + (threadIdx.x >> 6);
  if (w >= N) return;
  const int lane = threadIdx.x & 63;
  const int g = lane >> 4, sub = lane & 15;
  int start = rowptr[w];
  int end = (w == N - 1) ? Etot : rowptr[w + 1];
  int deg = end - start;
  f16x4 a0[3] = {}, a1[3] = {};
  float c1f = 0.f;
  int nj = (deg + 15) >> 4;
  for (int j = 0; j < nj; ++j) {
    int base = start + j * 16 + g * 4;
#pragma unroll
    for (int i = 0; i < 4; ++i) {
      int idx = j * 16 + g * 4 + i;
      if (idx < deg) {
        int e = csr[base + i];
        int src = e & 0x7fffffff;
        const f16* rowp = x + (size_t)src * 192 + sub * 4;
        f16x4 v0 = *reinterpret_cast<const f16x4*>(rowp);
        f16x4 v1 = *reinterpret_cast<const f16x4*>(rowp + 64);
        f16x4 v2 = *reinterpret_cast<const f16x4*>(rowp + 128);
        if (e < 0) {
          c1f += 1.f;
          a1[0] += v0; a1[1] += v1; a1[2] += v2;
        } else {
          a0[0] += v0; a0[1] += v1; a0[2] += v2;
        }
      }
    }
  }
#pragma unroll
  for (int c = 0; c < 3; ++c) {
    a0[c] += shflx4(a0[c], 16); a0[c] += shflx4(a0[c], 32);
    a1[c] += shflx4(a1[c], 16); a1[c] += shflx4(a1[c], 32);
  }
  c1f += __shfl_xor(c1f, 16); c1f += __shfl_xor(c1f, 32);
  if (g == 0) {
    float c0f = (float)deg - c1f;
    float i0 = 1.f / fmaxf(c0f, 1.f);
    float i1 = 1.f / fmaxf(c1f, 1.f);
#pragma unroll
    for (int c = 0; c < 3; ++c) {
      f16x4 o0, o1;
#pragma unroll
      for (int k = 0; k < 4; ++k) {
        o0[k] = (f16)((float)a0[c][k] * i0);
        o1[k] = (f16)((float)a1[c][k] * i1);
      }
      *reinterpret_cast<f16x4*>(agg0 + (size_t)w * 192 + c * 64 + sub * 4) = o0;
      *reinterpret_cast<f16x4*>(agg1 + (size_t)w * 192 + c * 64 + sub * 4) = o1;
    }
  }
}

extern "C" void kernel_launch(void* const* d_in, const int* in_sizes, int n_in,
                              void* d_out, int out_size, void* d_ws, size_t ws_size,
                              hipStream_t stream)
{
  const float* des      = (const float*)d_in[0];
  const float* num_prop = (const float*)d_in[2];
  const float* cat_prop = (const float*)d_in[3];
  const int* edge_index = (const int*)d_in[4];
  const int* edge_type  = (const int*)d_in[5];
  const float* W_des = (const float*)d_in[6];
  const float* b_des = (const float*)d_in[7];
  const float* W_num = (const float*)d_in[8];
  const float* b_num = (const float*)d_in[9];
  const float* W_cat = (const float*)d_in[10];
  const float* b_cat = (const float*)d_in[11];
  const float* W_in  = (const float*)d_in[12];
  const float* b_in  = (const float*)d_in[13];
  const float* W_root= (const float*)d_in[14];
  const float* W_rel = (const float*)d_in[15];
  const float* b_rgcn= (const float*)d_in[16];
  const float* W_o1  = (const float*)d_in[17];
  const float* b_o1  = (const float*)d_in[18];
  const float* W_o2  = (const float*)d_in[19];
  const float* b_o2  = (const float*)d_in[20];
  float* out = (float*)d_out;

  const int N = in_sizes[2] / 4;
  const int E = in_sizes[5];
  (void)n_in; (void)out_size; (void)ws_size;

  const int NB = (N + 255) >> 8;
  const int NBLK = (E + TILE - 1) / TILE;

  char* base = (char*)d_ws;
  size_t off = 0;
  auto take = [&](size_t bytes) -> void* {
    void* p = base + off;
    off += (bytes + 255) & ~(size_t)255;
    return p;
  };
  f16* xA      = (f16*)take((size_t)N * 192 * 2);
  f16* xB      = (f16*)take((size_t)N * 192 * 2);
  f16* agg0    = (f16*)take((size_t)N * 192 * 2);
  f16* agg1    = (f16*)take((size_t)N * 192 * 2);
  int* sorted  = (int*)take((size_t)E * 4);
  int* csr     = (int*)take((size_t)E * 4);
  int* rowptr  = (int*)take((size_t)(N + 4) * 4);
  int* hist    = (int*)take((size_t)NBLK * NB * 4);
  int* binbase = (int*)take((size_t)(NB + 2) * 4);
  f16* scratch = (f16*)take((size_t)N * 64 * 2);
  f16* WtDes   = (f16*)take(64 * 768 * 2);
  f16* WtIn    = (f16*)take(192 * 192 * 2);
  f16* WtR     = (f16*)take(192 * 576 * 2);
  f16* WtO1    = (f16*)take(192 * 192 * 2);

  const int nbf = (N + 3) / 4;
  const int nsetup = nbf + 192 + 144 + 432 + 144 + NBLK;
  setup_kernel<<<nsetup, 256, 0, stream>>>(
      num_prop, cat_prop, W_num, b_num, W_cat, b_cat,
      W_des, W_in, W_root, W_rel, W_o1,
      xA, WtDes, WtIn, WtR, WtO1,
      edge_index, hist, N, nbf, E, NB);
  scan_kernel<<<1, 512, 0, stream>>>(hist, binbase, NB, NBLK);
  const int nbDES = (N + 127) / 128;
  scatterdes_kernel<<<nbDES + NBLK, 256, 0, stream>>>(
      des, WtDes, b_des, xA, N, edge_index, edge_type, hist, sorted, E, NB, nbDES);
  // --- DIAGNOSTIC 1: des-GEMM at 2x K-work, scratch output -> duration ~ 2x des ---
  diag_des_kernel<<<nbDES, 256, 0, stream>>>(des, WtDes, b_des, scratch, N);
  const int nbX = (N + 127) / 128;
  gemm_x_kernel<1, true, false, true><<<nbX + NB, 512, 0, stream>>>(
      xA, xA, xA, WtIn, b_in, xB, N, nullptr, nullptr, nullptr,
      sorted, binbase, csr, rowptr, nbX);
  agg_kernel<<<(N + 3) / 4, 256, 0, stream>>>(xB, csr, rowptr, agg0, agg1, N, E);
  // --- DIAGNOSTIC 2: agg replayed x2 (idempotent) -> delta = 2x agg ---
  agg_kernel<<<(N + 3) / 4, 256, 0, stream>>>(xB, csr, rowptr, agg0, agg1, N, E);
  agg_kernel<<<(N + 3) / 4, 256, 0, stream>>>(xB, csr, rowptr, agg0, agg1, N, E);
  gemm_x_kernel<3, false, false, false><<<nbX, 512, 0, stream>>>(
      xB, agg0, agg1, WtR, b_rgcn, xA, N, nullptr, nullptr, nullptr,
      nullptr, nullptr, nullptr, nullptr, nbX);
  agg_kernel<<<(N + 3) / 4, 256, 0, stream>>>(xA, csr, rowptr, agg0, agg1, N, E);
  gemm_x_kernel<3, false, false, false><<<nbX, 512, 0, stream>>>(
      xA, agg0, agg1, WtR, b_rgcn, xB, N, nullptr, nullptr, nullptr,
      nullptr, nullptr, nullptr, nullptr, nbX);
  gemm_x_kernel<1, false, true, false><<<nbX, 512, 0, stream>>>(
      xB, xB, xB, WtO1, b_o1, nullptr, N, W_o2, b_o2, out,
      nullptr, nullptr, nullptr, nullptr, nbX);
}

// Round 14
// 713.549 us; speedup vs baseline: 1.1582x; 1.1582x over previous
//
#include <hip/hip_runtime.h>

typedef _Float16 f16;
typedef _Float16 f16x4 __attribute__((ext_vector_type(4)));
typedef _Float16 f16x8 __attribute__((ext_vector_type(8)));
typedef float f32x4 __attribute__((ext_vector_type(4)));

#define LRELU(v) ((v) >= 0.f ? (v) : 0.01f * (v))

__device__ __forceinline__ f16x4 shflx4(f16x4 v, int m) {
  union { f16x4 h; int i[2]; } u;
  u.h = v;
  u.i[0] = __shfl_xor(u.i[0], m);
  u.i[1] = __shfl_xor(u.i[1], m);
  return u.h;
}

#define TILE 4096

// ---------------- setup: feat_small + weight prep + coarse hist (trailing blocks) ----------------
__global__ __launch_bounds__(256) void setup_kernel(
    const float* __restrict__ num_prop, const float* __restrict__ cat_prop,
    const float* __restrict__ W_num, const float* __restrict__ b_num,
    const float* __restrict__ W_cat, const float* __restrict__ b_cat,
    const float* __restrict__ W_des, const float* __restrict__ W_in,
    const float* __restrict__ W_root, const float* __restrict__ W_rel,
    const float* __restrict__ W_o1,
    f16* __restrict__ x0,
    f16* __restrict__ WtDes, f16* __restrict__ WtIn, f16* __restrict__ WtR,
    f16* __restrict__ WtO1,
    const int* __restrict__ ei, int* __restrict__ hist,
    int N, int nbf, int E, int NB)
{
  __shared__ int h[512];
  int b = blockIdx.x;
  int tid = threadIdx.x;
  if (b < nbf) {
    int w = (b * 256 + tid) >> 6;
    int lane = tid & 63;
    if (w < N) {
      const float* npr = num_prop + (size_t)w * 4;
      const float* cpr = cat_prop + (size_t)w * 3;
      float vn = b_num[lane];
#pragma unroll
      for (int k = 0; k < 4; k++) vn += npr[k] * W_num[k * 64 + lane];
      float vc = b_cat[lane];
#pragma unroll
      for (int k = 0; k < 3; k++) vc += cpr[k] * W_cat[k * 64 + lane];
      vn = LRELU(vn);
      vc = LRELU(vc);
      x0[(size_t)w * 192 + 64 + lane] = (f16)vn;
      x0[(size_t)w * 192 + 128 + lane] = (f16)vc;
    }
    return;
  }
  b -= nbf;
  if (b < 192) {
    int idx = b * 256 + tid;
    if (idx < 64 * 768) { int n = idx / 768, k = idx % 768; WtDes[idx] = (f16)W_des[k * 64 + n]; }
    return;
  }
  b -= 192;
  if (b < 144) {
    int idx = b * 256 + tid;
    if (idx < 192 * 192) { int n = idx / 192, k = idx % 192; WtIn[idx] = (f16)W_in[k * 192 + n]; }
    return;
  }
  b -= 144;
  if (b < 432) {
    int idx = b * 256 + tid;
    if (idx < 192 * 576) {
      int n = idx / 576, k = idx % 576;
      int seg = k / 192, kk = k % 192;
      float v = (seg == 0) ? W_root[kk * 192 + n] : W_rel[(seg - 1) * 192 * 192 + kk * 192 + n];
      WtR[idx] = (f16)v;
    }
    return;
  }
  b -= 432;
  if (b < 144) {
    int idx = b * 256 + tid;
    if (idx < 192 * 192) { int n = idx / 192, k = idx % 192; WtO1[idx] = (f16)W_o1[k * 192 + n]; }
    return;
  }
  b -= 144;
  for (int i = tid; i < NB; i += 256) h[i] = 0;
  __syncthreads();
  const int base = b * TILE;
#pragma unroll
  for (int i = 0; i < TILE / 256; ++i) {
    int e = base + i * 256 + tid;
    if (e < E) atomicAdd(&h[ei[E + e] >> 8], 1);
  }
  __syncthreads();
  for (int i = tid; i < NB; i += 256) hist[b * NB + i] = h[i];
}

// ---------------- bin scan + per-(tile,bin) exclusive bases (in place) ----------------
__global__ __launch_bounds__(512) void scan_kernel(
    int* __restrict__ hist, int* __restrict__ binbase, int NB, int NBLK)
{
  __shared__ int s[512];
  const int b = threadIdx.x;
  int total = 0;
  if (b < NB) {
#pragma unroll 8
    for (int blk = 0; blk < NBLK; ++blk) total += hist[blk * NB + b];
  }
  s[b] = total;
  __syncthreads();
  for (int off = 1; off < 512; off <<= 1) {
    int v = (b >= off) ? s[b - off] : 0;
    __syncthreads();
    s[b] += v;
    __syncthreads();
  }
  int ex = (b == 0) ? 0 : s[b - 1];
  if (b < NB) binbase[b] = ex;
  if (b == 0) binbase[NB] = s[511];
  if (b < NB) {
    int run = ex;
#pragma unroll 8
    for (int blk = 0; blk < NBLK; ++blk) {
      int t = hist[blk * NB + b];
      hist[blk * NB + b] = run;
      run += t;
    }
  }
}

// ---------------- merged des-GEMM (barrier-free, direct-fragment) + bin scatter ----------------
__global__ __launch_bounds__(256) void scatterdes_kernel(
    const float* __restrict__ A, const f16* __restrict__ Bt,
    const float* __restrict__ bias, f16* __restrict__ C, int M,
    const int* __restrict__ ei, const int* __restrict__ et,
    const int* __restrict__ hist, int* __restrict__ sorted,
    int E, int NB, int nbDES)
{
  __shared__ int scur[512];
  const int tid = threadIdx.x;
  if ((int)blockIdx.x >= nbDES) {
    int blk = (int)blockIdx.x - nbDES;
    for (int i = tid; i < NB; i += 256) scur[i] = hist[blk * NB + i];
    __syncthreads();
    const int base = blk * TILE;
#pragma unroll
    for (int i = 0; i < TILE / 256; ++i) {
      int e = base + i * 256 + tid;
      if (e < E) {
        int src = ei[e];
        int dst = ei[E + e];
        int r = et[e];
        int slot = atomicAdd(&scur[dst >> 8], 1);
        sorted[slot] = src | (r << 17) | ((dst & 255) << 18);
      }
    }
    return;
  }
  const int lane = tid & 63, wid = tid >> 6;
  const int wm = wid >> 1, wn = wid & 1;
  const int m0 = blockIdx.x * 128;
  const int l15 = lane & 15, lhi = lane >> 4;
  f32x4 acc[4][2] = {};
  const float* aB[4];
#pragma unroll
  for (int fm = 0; fm < 4; ++fm) {
    int gr = m0 + wm * 64 + fm * 16 + l15;
    if (gr >= M) gr = M - 1;
    aB[fm] = A + (size_t)gr * 768 + lhi * 8;
  }
  const f16* bB[2];
#pragma unroll
  for (int fn = 0; fn < 2; ++fn)
    bB[fn] = Bt + (size_t)(wn * 32 + fn * 16 + l15) * 768 + lhi * 8;

  float4 ac[4][2];
  f16x8 bc[2];
#pragma unroll
  for (int fm = 0; fm < 4; ++fm) {
    const float4* p = reinterpret_cast<const float4*>(aB[fm]);
    ac[fm][0] = p[0]; ac[fm][1] = p[1];
  }
#pragma unroll
  for (int fn = 0; fn < 2; ++fn)
    bc[fn] = *reinterpret_cast<const f16x8*>(bB[fn]);

#pragma unroll 4
  for (int k0 = 0; k0 < 768; k0 += 32) {
    float4 an[4][2];
    f16x8 bn[2];
    if (k0 + 32 < 768) {
#pragma unroll
      for (int fm = 0; fm < 4; ++fm) {
        const float4* p = reinterpret_cast<const float4*>(aB[fm] + k0 + 32);
        an[fm][0] = p[0]; an[fm][1] = p[1];
      }
#pragma unroll
      for (int fn = 0; fn < 2; ++fn)
        bn[fn] = *reinterpret_cast<const f16x8*>(bB[fn] + k0 + 32);
    }
    f16x8 af[4];
#pragma unroll
    for (int fm = 0; fm < 4; ++fm) {
      af[fm][0] = (f16)ac[fm][0].x; af[fm][1] = (f16)ac[fm][0].y;
      af[fm][2] = (f16)ac[fm][0].z; af[fm][3] = (f16)ac[fm][0].w;
      af[fm][4] = (f16)ac[fm][1].x; af[fm][5] = (f16)ac[fm][1].y;
      af[fm][6] = (f16)ac[fm][1].z; af[fm][7] = (f16)ac[fm][1].w;
    }
#pragma unroll
    for (int fm = 0; fm < 4; ++fm)
#pragma unroll
      for (int fn = 0; fn < 2; ++fn)
        acc[fm][fn] = __builtin_amdgcn_mfma_f32_16x16x32_f16(af[fm], bc[fn], acc[fm][fn], 0, 0, 0);
    if (k0 + 32 < 768) {
#pragma unroll
      for (int fm = 0; fm < 4; ++fm) { ac[fm][0] = an[fm][0]; ac[fm][1] = an[fm][1]; }
#pragma unroll
      for (int fn = 0; fn < 2; ++fn) bc[fn] = bn[fn];
    }
  }
#pragma unroll
  for (int fm = 0; fm < 4; fm++) {
#pragma unroll
    for (int fn = 0; fn < 2; fn++) {
      int gc = wn * 32 + fn * 16 + l15;
      float b = bias[gc];
#pragma unroll
      for (int r = 0; r < 4; r++) {
        int gr = m0 + wm * 64 + fm * 16 + lhi * 4 + r;
        if (gr < M) {
          float v = acc[fm][fn][r] + b;
          C[(size_t)gr * 192 + gc] = (f16)LRELU(v);
        }
      }
    }
  }
}

// ---------------- generic x-GEMM: barrier-free direct-fragment, BM=64, 256 thr ----------------
// (+ optional CSR fine-build trailing blocks)
template <int NSEG, bool RELU, bool OUT2, bool BUILD>
__global__ __launch_bounds__(256) void gemm_x_kernel(
    const f16* __restrict__ A0, const f16* __restrict__ A1, const f16* __restrict__ A2,
    const f16* __restrict__ Bt, const float* __restrict__ bias,
    f16* __restrict__ C, int M,
    const float* __restrict__ W_o2, const float* __restrict__ b_o2,
    float* __restrict__ out,
    const int* __restrict__ sorted, const int* __restrict__ binbase,
    int* __restrict__ csr, int* __restrict__ rowptr, int nbGEMM)
{
  __shared__ int smem_i[768];
  __shared__ float red[64][2];
  const int tid = threadIdx.x;
  if (BUILD && (int)blockIdx.x >= nbGEMM) {
    int bb = (int)blockIdx.x - nbGEMM;
    int* dcount = smem_i;
    int* lbase  = smem_i + 256;
    int* cur    = smem_i + 512;
    dcount[tid] = 0; cur[tid] = 0;
    __syncthreads();
    int start = binbase[bb], end = binbase[bb + 1];
    for (int j = start + tid; j < end; j += 256)
      atomicAdd(&dcount[(sorted[j] >> 18) & 255], 1);
    __syncthreads();
    lbase[tid] = dcount[tid];
    __syncthreads();
    for (int off = 1; off < 256; off <<= 1) {
      int v = (tid >= off) ? lbase[tid - off] : 0;
      __syncthreads();
      lbase[tid] += v;
      __syncthreads();
    }
    {
      int dst = (bb << 8) + tid;
      if (dst < M) rowptr[dst] = start + lbase[tid] - dcount[tid];
    }
    __syncthreads();
    for (int j = start + tid; j < end; j += 256) {
      int it = sorted[j];
      int dl = (it >> 18) & 255;
      int pos = atomicAdd(&cur[dl], 1);
      int exb = start + lbase[dl] - dcount[dl];
      csr[exb + pos] = (it & 0x1FFFF) | (int)(((unsigned)((it >> 17) & 1)) << 31);
    }
    return;
  }
  const int lane = tid & 63, wn = tid >> 6;   // 4 waves = 4 col groups
  const int l15 = lane & 15, lhi = lane >> 4;
  const int m0 = blockIdx.x * 64;
  const int Ktot = NSEG * 192;
  f32x4 acc[4][3] = {};
  const f16* segs[3] = {A0, A1, A2};
  int gro[4];
#pragma unroll
  for (int fm = 0; fm < 4; ++fm) {
    int gr = m0 + fm * 16 + l15;
    if (gr >= M) gr = M - 1;
    gro[fm] = gr;
  }
  const f16* bB[3];
#pragma unroll
  for (int fn = 0; fn < 3; ++fn)
    bB[fn] = Bt + (size_t)(wn * 48 + fn * 16 + l15) * Ktot + lhi * 8;

#pragma unroll
  for (int seg = 0; seg < NSEG; ++seg) {
    const f16* As = segs[seg];
    const f16* aP[4];
#pragma unroll
    for (int fm = 0; fm < 4; ++fm)
      aP[fm] = As + (size_t)gro[fm] * 192 + lhi * 8;
#pragma unroll
    for (int c = 0; c < 6; ++c) {
      f16x8 af[4], bf[3];
#pragma unroll
      for (int fm = 0; fm < 4; ++fm)
        af[fm] = *reinterpret_cast<const f16x8*>(aP[fm] + c * 32);
#pragma unroll
      for (int fn = 0; fn < 3; ++fn)
        bf[fn] = *reinterpret_cast<const f16x8*>(bB[fn] + seg * 192 + c * 32);
#pragma unroll
      for (int fm = 0; fm < 4; ++fm)
#pragma unroll
        for (int fn = 0; fn < 3; ++fn)
          acc[fm][fn] = __builtin_amdgcn_mfma_f32_16x16x32_f16(af[fm], bf[fn], acc[fm][fn], 0, 0, 0);
    }
  }
  if (OUT2) {
    if (tid < 128) ((float*)red)[tid] = 0.f;
    __syncthreads();
    float bb2[3], w2v[3][2];
#pragma unroll
    for (int fn = 0; fn < 3; fn++) {
      int gc = wn * 48 + fn * 16 + l15;
      bb2[fn] = bias[gc];
      w2v[fn][0] = W_o2[gc * 2 + 0];
      w2v[fn][1] = W_o2[gc * 2 + 1];
    }
#pragma unroll
    for (int fm = 0; fm < 4; fm++) {
#pragma unroll
      for (int r = 0; r < 4; r++) {
        float p0 = 0.f, p1 = 0.f;
#pragma unroll
        for (int fn = 0; fn < 3; fn++) {
          float v = acc[fm][fn][r] + bb2[fn];
          v = LRELU(v);
          p0 += v * w2v[fn][0];
          p1 += v * w2v[fn][1];
        }
#pragma unroll
        for (int m = 1; m < 16; m <<= 1) { p0 += __shfl_xor(p0, m); p1 += __shfl_xor(p1, m); }
        if (l15 == 0) {
          int lr = fm * 16 + lhi * 4 + r;
          atomicAdd(&red[lr][0], p0);
          atomicAdd(&red[lr][1], p1);
        }
      }
    }
    __syncthreads();
    if (tid < 128) {
      int gr = m0 + (tid >> 1);
      if (gr < M) out[(size_t)gr * 2 + (tid & 1)] = red[tid >> 1][tid & 1] + b_o2[tid & 1];
    }
  } else {
#pragma unroll
    for (int fm = 0; fm < 4; fm++) {
#pragma unroll
      for (int fn = 0; fn < 3; fn++) {
        int gc = wn * 48 + fn * 16 + l15;
        float b = bias[gc];
#pragma unroll
        for (int r = 0; r < 4; r++) {
          int gr = m0 + fm * 16 + lhi * 4 + r;
          if (gr < M) {
            float v = acc[fm][fn][r] + b;
            if (RELU) v = LRELU(v);
            C[(size_t)gr * 192 + gc] = (f16)v;
          }
        }
      }
    }
  }
}

// ---------------- CSR-based per-(dst,rel) mean aggregation v6 ----------------
__global__ __launch_bounds__(256) void agg_kernel(
    const f16* __restrict__ x, const int* __restrict__ csr,
    const int* __restrict__ rowptr,
    f16* __restrict__ agg0, f16* __restrict__ agg1, int N, int Etot)
{
  int w = (blockIdx.x << 2) + (threadIdx.x >> 6);
  if (w >= N) return;
  const int lane = threadIdx.x & 63;
  const int g = lane >> 4, sub = lane & 15;
  int start = rowptr[w];
  int end = (w == N - 1) ? Etot : rowptr[w + 1];
  int deg = end - start;
  f16x4 a0[3] = {}, a1[3] = {};
  float c1f = 0.f;
  int nj = (deg + 15) >> 4;
  for (int j = 0; j < nj; ++j) {
    int base = start + j * 16 + g * 4;
#pragma unroll
    for (int i = 0; i < 4; ++i) {
      int idx = j * 16 + g * 4 + i;
      if (idx < deg) {
        int e = csr[base + i];
        int src = e & 0x7fffffff;
        const f16* rowp = x + (size_t)src * 192 + sub * 4;
        f16x4 v0 = *reinterpret_cast<const f16x4*>(rowp);
        f16x4 v1 = *reinterpret_cast<const f16x4*>(rowp + 64);
        f16x4 v2 = *reinterpret_cast<const f16x4*>(rowp + 128);
        if (e < 0) {
          c1f += 1.f;
          a1[0] += v0; a1[1] += v1; a1[2] += v2;
        } else {
          a0[0] += v0; a0[1] += v1; a0[2] += v2;
        }
      }
    }
  }
#pragma unroll
  for (int c = 0; c < 3; ++c) {
    a0[c] += shflx4(a0[c], 16); a0[c] += shflx4(a0[c], 32);
    a1[c] += shflx4(a1[c], 16); a1[c] += shflx4(a1[c], 32);
  }
  c1f += __shfl_xor(c1f, 16); c1f += __shfl_xor(c1f, 32);
  if (g == 0) {
    float c0f = (float)deg - c1f;
    float i0 = 1.f / fmaxf(c0f, 1.f);
    float i1 = 1.f / fmaxf(c1f, 1.f);
#pragma unroll
    for (int c = 0; c < 3; ++c) {
      f16x4 o0, o1;
#pragma unroll
      for (int k = 0; k < 4; ++k) {
        o0[k] = (f16)((float)a0[c][k] * i0);
        o1[k] = (f16)((float)a1[c][k] * i1);
      }
      *reinterpret_cast<f16x4*>(agg0 + (size_t)w * 192 + c * 64 + sub * 4) = o0;
      *reinterpret_cast<f16x4*>(agg1 + (size_t)w * 192 + c * 64 + sub * 4) = o1;
    }
  }
}

extern "C" void kernel_launch(void* const* d_in, const int* in_sizes, int n_in,
                              void* d_out, int out_size, void* d_ws, size_t ws_size,
                              hipStream_t stream)
{
  const float* des      = (const float*)d_in[0];
  const float* num_prop = (const float*)d_in[2];
  const float* cat_prop = (const float*)d_in[3];
  const int* edge_index = (const int*)d_in[4];
  const int* edge_type  = (const int*)d_in[5];
  const float* W_des = (const float*)d_in[6];
  const float* b_des = (const float*)d_in[7];
  const float* W_num = (const float*)d_in[8];
  const float* b_num = (const float*)d_in[9];
  const float* W_cat = (const float*)d_in[10];
  const float* b_cat = (const float*)d_in[11];
  const float* W_in  = (const float*)d_in[12];
  const float* b_in  = (const float*)d_in[13];
  const float* W_root= (const float*)d_in[14];
  const float* W_rel = (const float*)d_in[15];
  const float* b_rgcn= (const float*)d_in[16];
  const float* W_o1  = (const float*)d_in[17];
  const float* b_o1  = (const float*)d_in[18];
  const float* W_o2  = (const float*)d_in[19];
  const float* b_o2  = (const float*)d_in[20];
  float* out = (float*)d_out;

  const int N = in_sizes[2] / 4;
  const int E = in_sizes[5];
  (void)n_in; (void)out_size; (void)ws_size;

  const int NB = (N + 255) >> 8;
  const int NBLK = (E + TILE - 1) / TILE;

  char* base = (char*)d_ws;
  size_t off = 0;
  auto take = [&](size_t bytes) -> void* {
    void* p = base + off;
    off += (bytes + 255) & ~(size_t)255;
    return p;
  };
  f16* xA      = (f16*)take((size_t)N * 192 * 2);
  f16* xB      = (f16*)take((size_t)N * 192 * 2);
  f16* agg0    = (f16*)take((size_t)N * 192 * 2);
  f16* agg1    = (f16*)take((size_t)N * 192 * 2);
  int* sorted  = (int*)take((size_t)E * 4);
  int* csr     = (int*)take((size_t)E * 4);
  int* rowptr  = (int*)take((size_t)(N + 4) * 4);
  int* hist    = (int*)take((size_t)NBLK * NB * 4);
  int* binbase = (int*)take((size_t)(NB + 2) * 4);
  f16* WtDes   = (f16*)take(64 * 768 * 2);
  f16* WtIn    = (f16*)take(192 * 192 * 2);
  f16* WtR     = (f16*)take(192 * 576 * 2);
  f16* WtO1    = (f16*)take(192 * 192 * 2);

  const int nbf = (N + 3) / 4;
  const int nsetup = nbf + 192 + 144 + 432 + 144 + NBLK;
  setup_kernel<<<nsetup, 256, 0, stream>>>(
      num_prop, cat_prop, W_num, b_num, W_cat, b_cat,
      W_des, W_in, W_root, W_rel, W_o1,
      xA, WtDes, WtIn, WtR, WtO1,
      edge_index, hist, N, nbf, E, NB);
  scan_kernel<<<1, 512, 0, stream>>>(hist, binbase, NB, NBLK);
  const int nbDES = (N + 127) / 128;
  scatterdes_kernel<<<nbDES + NBLK, 256, 0, stream>>>(
      des, WtDes, b_des, xA, N, edge_index, edge_type, hist, sorted, E, NB, nbDES);
  const int nbX = (N + 63) / 64;
  gemm_x_kernel<1, true, false, true><<<nbX + NB, 256, 0, stream>>>(
      xA, xA, xA, WtIn, b_in, xB, N, nullptr, nullptr, nullptr,
      sorted, binbase, csr, rowptr, nbX);
  agg_kernel<<<(N + 3) / 4, 256, 0, stream>>>(xB, csr, rowptr, agg0, agg1, N, E);
  gemm_x_kernel<3, false, false, false><<<nbX, 256, 0, stream>>>(
      xB, agg0, agg1, WtR, b_rgcn, xA, N, nullptr, nullptr, nullptr,
      nullptr, nullptr, nullptr, nullptr, nbX);
  agg_kernel<<<(N + 3) / 4, 256, 0, stream>>>(xA, csr, rowptr, agg0, agg1, N, E);
  gemm_x_kernel<3, false, false, false><<<nbX, 256, 0, stream>>>(
      xA, agg0, agg1, WtR, b_rgcn, xB, N, nullptr, nullptr, nullptr,
      nullptr, nullptr, nullptr, nullptr, nbX);
  gemm_x_kernel<1, false, true, false><<<nbX, 256, 0, stream>>>(
      xB, xB, xB, WtO1, b_o1, nullptr, N, W_o2, b_o2, out,
      nullptr, nullptr, nullptr, nullptr, nbX);
}

// Round 15
// 497.340 us; speedup vs baseline: 1.6617x; 1.4347x over previous
//
#include <hip/hip_runtime.h>

typedef _Float16 f16;
typedef _Float16 f16x4 __attribute__((ext_vector_type(4)));
typedef _Float16 f16x8 __attribute__((ext_vector_type(8)));
typedef float f32x4 __attribute__((ext_vector_type(4)));

#define LRELU(v) ((v) >= 0.f ? (v) : 0.01f * (v))

__device__ __forceinline__ int swz(int a) { return a ^ (((a >> 7) & 7) << 4); }

__device__ __forceinline__ f16x4 shflx4(f16x4 v, int m) {
  union { f16x4 h; int i[2]; } u;
  u.h = v;
  u.i[0] = __shfl_xor(u.i[0], m);
  u.i[1] = __shfl_xor(u.i[1], m);
  return u.h;
}

#define BCAP 64
#define TILE 4096

// ---------------- setup: feat_small + weight prep + coarse hist (trailing blocks) ----------------
__global__ __launch_bounds__(256) void setup_kernel(
    const float* __restrict__ num_prop, const float* __restrict__ cat_prop,
    const float* __restrict__ W_num, const float* __restrict__ b_num,
    const float* __restrict__ W_cat, const float* __restrict__ b_cat,
    const float* __restrict__ W_des, const float* __restrict__ W_in,
    const float* __restrict__ W_root, const float* __restrict__ W_rel,
    const float* __restrict__ W_o1,
    f16* __restrict__ x0,
    f16* __restrict__ WtDes, f16* __restrict__ WtIn, f16* __restrict__ WtR,
    f16* __restrict__ WtO1,
    const int* __restrict__ ei, int* __restrict__ hist,
    int N, int nbf, int E, int NB)
{
  __shared__ int h[512];
  int b = blockIdx.x;
  int tid = threadIdx.x;
  if (b < nbf) {
    int w = (b * 256 + tid) >> 6;
    int lane = tid & 63;
    if (w < N) {
      const float* npr = num_prop + (size_t)w * 4;
      const float* cpr = cat_prop + (size_t)w * 3;
      float vn = b_num[lane];
#pragma unroll
      for (int k = 0; k < 4; k++) vn += npr[k] * W_num[k * 64 + lane];
      float vc = b_cat[lane];
#pragma unroll
      for (int k = 0; k < 3; k++) vc += cpr[k] * W_cat[k * 64 + lane];
      vn = LRELU(vn);
      vc = LRELU(vc);
      x0[(size_t)w * 192 + 64 + lane] = (f16)vn;
      x0[(size_t)w * 192 + 128 + lane] = (f16)vc;
    }
    return;
  }
  b -= nbf;
  if (b < 192) {
    int idx = b * 256 + tid;
    if (idx < 64 * 768) { int n = idx / 768, k = idx % 768; WtDes[idx] = (f16)W_des[k * 64 + n]; }
    return;
  }
  b -= 192;
  if (b < 144) {
    int idx = b * 256 + tid;
    if (idx < 192 * 192) { int n = idx / 192, k = idx % 192; WtIn[idx] = (f16)W_in[k * 192 + n]; }
    return;
  }
  b -= 144;
  if (b < 432) {
    int idx = b * 256 + tid;
    if (idx < 192 * 576) {
      int n = idx / 576, k = idx % 576;
      int seg = k / 192, kk = k % 192;
      float v = (seg == 0) ? W_root[kk * 192 + n] : W_rel[(seg - 1) * 192 * 192 + kk * 192 + n];
      WtR[idx] = (f16)v;
    }
    return;
  }
  b -= 432;
  if (b < 144) {
    int idx = b * 256 + tid;
    if (idx < 192 * 192) { int n = idx / 192, k = idx % 192; WtO1[idx] = (f16)W_o1[k * 192 + n]; }
    return;
  }
  b -= 144;
  for (int i = tid; i < NB; i += 256) h[i] = 0;
  __syncthreads();
  const int base = b * TILE;
#pragma unroll
  for (int i = 0; i < TILE / 256; ++i) {
    int e = base + i * 256 + tid;
    if (e < E) atomicAdd(&h[ei[E + e] >> 8], 1);
  }
  __syncthreads();
  for (int i = tid; i < NB; i += 256) hist[b * NB + i] = h[i];
}

// ---------------- bin scan + per-(tile,bin) exclusive bases (in place) ----------------
__global__ __launch_bounds__(512) void scan_kernel(
    int* __restrict__ hist, int* __restrict__ binbase, int NB, int NBLK)
{
  __shared__ int s[512];
  const int b = threadIdx.x;
  int total = 0;
  if (b < NB) {
#pragma unroll 8
    for (int blk = 0; blk < NBLK; ++blk) total += hist[blk * NB + b];
  }
  s[b] = total;
  __syncthreads();
  for (int off = 1; off < 512; off <<= 1) {
    int v = (b >= off) ? s[b - off] : 0;
    __syncthreads();
    s[b] += v;
    __syncthreads();
  }
  int ex = (b == 0) ? 0 : s[b - 1];
  if (b < NB) binbase[b] = ex;
  if (b == 0) binbase[NB] = s[511];
  if (b < NB) {
    int run = ex;
#pragma unroll 8
    for (int blk = 0; blk < NBLK; ++blk) {
      int t = hist[blk * NB + b];
      hist[blk * NB + b] = run;
      run += t;
    }
  }
}

// ---------------- merged des-GEMM (pipelined reg-prefetch staging) + bin scatter ----------------
__global__ __launch_bounds__(256) void scatterdes_kernel(
    const float* __restrict__ A, const f16* __restrict__ Bt,
    const float* __restrict__ bias, f16* __restrict__ C, int M,
    const int* __restrict__ ei, const int* __restrict__ et,
    const int* __restrict__ hist, int* __restrict__ sorted,
    int E, int NB, int nbDES)
{
  __shared__ f16 lA[128 * 64];
  __shared__ f16 lB[64 * 64];
  const int tid = threadIdx.x;
  if ((int)blockIdx.x >= nbDES) {
    int blk = (int)blockIdx.x - nbDES;
    int* cur = (int*)lA;
    for (int i = tid; i < NB; i += 256) cur[i] = hist[blk * NB + i];
    __syncthreads();
    const int base = blk * TILE;
#pragma unroll
    for (int i = 0; i < TILE / 256; ++i) {
      int e = base + i * 256 + tid;
      if (e < E) {
        int src = ei[e];
        int dst = ei[E + e];
        int r = et[e];
        int slot = atomicAdd(&cur[dst >> 8], 1);
        sorted[slot] = src | (r << 17) | ((dst & 255) << 18);
      }
    }
    return;
  }
  const int lane = tid & 63, wid = tid >> 6;
  const int wm = wid >> 1, wn = wid & 1;
  const int m0 = blockIdx.x * 128;
  f32x4 acc[4][2] = {};
  const int arow = tid >> 3;
  const int acolf = (tid & 7) * 8;
  const float* aptr[4];
#pragma unroll
  for (int p = 0; p < 4; ++p) {
    int gr = m0 + p * 32 + arow;
    if (gr >= M) gr = M - 1;
    aptr[p] = A + (size_t)gr * 768 + acolf;
  }
  float4 pa[4][2];
  f16x8 pb[2];
  auto load_chunk = [&](int k0) {
#pragma unroll
    for (int p = 0; p < 4; ++p) {
      const float4* s = reinterpret_cast<const float4*>(aptr[p] + k0);
      pa[p][0] = s[0];
      pa[p][1] = s[1];
    }
#pragma unroll
    for (int i = 0; i < 2; ++i) {
      int c = tid + i * 256;
      int n = c >> 3, k8 = c & 7;
      pb[i] = *reinterpret_cast<const f16x8*>(Bt + (size_t)n * 768 + k0 + k8 * 8);
    }
  };
  load_chunk(0);
  for (int k0 = 0; k0 < 768; k0 += 64) {
#pragma unroll
    for (int p = 0; p < 4; ++p) {
      f16x8 h;
      h[0] = (f16)pa[p][0].x; h[1] = (f16)pa[p][0].y; h[2] = (f16)pa[p][0].z; h[3] = (f16)pa[p][0].w;
      h[4] = (f16)pa[p][1].x; h[5] = (f16)pa[p][1].y; h[6] = (f16)pa[p][1].z; h[7] = (f16)pa[p][1].w;
      int row = p * 32 + arow;
      *reinterpret_cast<f16x8*>((char*)lA + swz(row * 128 + (tid & 7) * 16)) = h;
    }
#pragma unroll
    for (int i = 0; i < 2; ++i) {
      int c = tid + i * 256;
      int n = c >> 3, k8 = c & 7;
      *reinterpret_cast<f16x8*>((char*)lB + swz(n * 128 + k8 * 16)) = pb[i];
    }
    if (k0 + 64 < 768) load_chunk(k0 + 64);
    __syncthreads();
#pragma unroll
    for (int ks = 0; ks < 2; ks++) {
      f16x8 af[4], bf[2];
#pragma unroll
      for (int fm = 0; fm < 4; fm++) {
        int row = wm * 64 + fm * 16 + (lane & 15);
        af[fm] = *reinterpret_cast<const f16x8*>((const char*)lA + swz(row * 128 + ks * 64 + (lane >> 4) * 16));
      }
#pragma unroll
      for (int fn = 0; fn < 2; fn++) {
        int nn = wn * 32 + fn * 16 + (lane & 15);
        bf[fn] = *reinterpret_cast<const f16x8*>((const char*)lB + swz(nn * 128 + ks * 64 + (lane >> 4) * 16));
      }
#pragma unroll
      for (int fm = 0; fm < 4; fm++)
#pragma unroll
        for (int fn = 0; fn < 2; fn++)
          acc[fm][fn] = __builtin_amdgcn_mfma_f32_16x16x32_f16(af[fm], bf[fn], acc[fm][fn], 0, 0, 0);
    }
    __syncthreads();
  }
#pragma unroll
  for (int fm = 0; fm < 4; fm++) {
#pragma unroll
    for (int fn = 0; fn < 2; fn++) {
      int gc = wn * 32 + fn * 16 + (lane & 15);
      float b = bias[gc];
#pragma unroll
      for (int r = 0; r < 4; r++) {
        int gr = m0 + wm * 64 + fm * 16 + (lane >> 4) * 4 + r;
        if (gr < M) {
          float v = acc[fm][fn][r] + b;
          C[(size_t)gr * 192 + gc] = (f16)LRELU(v);
        }
      }
    }
  }
}

// ---------------- generic x-GEMM, pipelined reg-prefetch (+ optional bucket-build tail blocks) ----------------
// BUILD tail: bin bb -> distribute sorted[binbase[bb]..] into BCAP-padded bucket + cursor (deg).
template <int NSEG, bool RELU, bool OUT2, bool BUILD>
__global__ __launch_bounds__(512) void gemm_x_kernel(
    const f16* __restrict__ A0, const f16* __restrict__ A1, const f16* __restrict__ A2,
    const f16* __restrict__ Bt, const float* __restrict__ bias,
    f16* __restrict__ C, int M,
    const float* __restrict__ W_o2, const float* __restrict__ b_o2,
    float* __restrict__ out,
    const int* __restrict__ sorted, const int* __restrict__ binbase,
    int* __restrict__ bucket, int* __restrict__ cursor, int nbGEMM)
{
  __shared__ f16 lA[128 * 64];
  __shared__ f16 lB[192 * 64];
  const int tid = threadIdx.x;
  if (BUILD && (int)blockIdx.x >= nbGEMM) {
    int bb = (int)blockIdx.x - nbGEMM;
    int* cur = (int*)lA;   // 256 counters
    if (tid < 256) cur[tid] = 0;
    __syncthreads();
    int start = binbase[bb], end = binbase[bb + 1];
    for (int j = start + tid; j < end; j += 512) {
      int it = sorted[j];
      int dl = (it >> 18) & 255;
      int pos = atomicAdd(&cur[dl], 1);
      if (pos < BCAP) {
        int val = (it & 0x1FFFF) | (int)(((unsigned)((it >> 17) & 1)) << 31);
        bucket[(((size_t)(bb << 8) + dl) << 6) + pos] = val;
      }
    }
    __syncthreads();
    if (tid < 256) {
      int dst = (bb << 8) + tid;
      if (dst < M) cursor[dst] = cur[tid];
    }
    return;
  }
  const int lane = tid & 63, wid = tid >> 6;
  const int wm = wid >> 2, wn = wid & 3;
  const int m0 = blockIdx.x * 128;
  const int Ktot = NSEG * 192;
  const int NIT = NSEG * 3;
  f32x4 acc[4][3] = {};
  const f16* segs[3] = {A0, A1, A2};
  const int arow = tid >> 2, aq = tid & 3;
  int agr = m0 + arow;
  if (agr >= M) agr = M - 1;
  f16x8 pa0, pa1, pb[3];
  auto load_it = [&](int it) {
    const f16x8* s8 = reinterpret_cast<const f16x8*>(segs[it / 3] + (size_t)agr * 192 + (it % 3) * 64 + aq * 16);
    pa0 = s8[0];
    pa1 = s8[1];
#pragma unroll
    for (int i = 0; i < 3; i++) {
      int c = tid + i * 512;
      int n = c >> 3, k8 = c & 7;
      pb[i] = *reinterpret_cast<const f16x8*>(Bt + (size_t)n * Ktot + it * 64 + k8 * 8);
    }
  };
  load_it(0);
  for (int it = 0; it < NIT; it++) {
    {
      int b0 = arow * 128 + aq * 32;
      *reinterpret_cast<f16x8*>((char*)lA + swz(b0)) = pa0;
      *reinterpret_cast<f16x8*>((char*)lA + swz(b0 + 16)) = pa1;
#pragma unroll
      for (int i = 0; i < 3; i++) {
        int c = tid + i * 512;
        int n = c >> 3, k8 = c & 7;
        *reinterpret_cast<f16x8*>((char*)lB + swz(n * 128 + k8 * 16)) = pb[i];
      }
    }
    if (it + 1 < NIT) load_it(it + 1);
    __syncthreads();
#pragma unroll
    for (int ks = 0; ks < 2; ks++) {
      f16x8 af[4], bf[3];
#pragma unroll
      for (int fm = 0; fm < 4; fm++) {
        int row = wm * 64 + fm * 16 + (lane & 15);
        af[fm] = *reinterpret_cast<const f16x8*>((const char*)lA + swz(row * 128 + ks * 64 + (lane >> 4) * 16));
      }
#pragma unroll
      for (int fn = 0; fn < 3; fn++) {
        int nn = wn * 48 + fn * 16 + (lane & 15);
        bf[fn] = *reinterpret_cast<const f16x8*>((const char*)lB + swz(nn * 128 + ks * 64 + (lane >> 4) * 16));
      }
#pragma unroll
      for (int fm = 0; fm < 4; fm++)
#pragma unroll
        for (int fn = 0; fn < 3; fn++)
          acc[fm][fn] = __builtin_amdgcn_mfma_f32_16x16x32_f16(af[fm], bf[fn], acc[fm][fn], 0, 0, 0);
    }
    __syncthreads();
  }
  if (OUT2) {
    __shared__ float red[128][2];
    for (int i = tid; i < 256; i += 512) ((float*)red)[i] = 0.f;
    __syncthreads();
    float bb2[3], w2v[3][2];
#pragma unroll
    for (int fn = 0; fn < 3; fn++) {
      int gc = wn * 48 + fn * 16 + (lane & 15);
      bb2[fn] = bias[gc];
      w2v[fn][0] = W_o2[gc * 2 + 0];
      w2v[fn][1] = W_o2[gc * 2 + 1];
    }
#pragma unroll
    for (int fm = 0; fm < 4; fm++) {
#pragma unroll
      for (int r = 0; r < 4; r++) {
        float p0 = 0.f, p1 = 0.f;
#pragma unroll
        for (int fn = 0; fn < 3; fn++) {
          float v = acc[fm][fn][r] + bb2[fn];
          v = LRELU(v);
          p0 += v * w2v[fn][0];
          p1 += v * w2v[fn][1];
        }
#pragma unroll
        for (int m = 1; m < 16; m <<= 1) { p0 += __shfl_xor(p0, m); p1 += __shfl_xor(p1, m); }
        if ((lane & 15) == 0) {
          int lr = wm * 64 + fm * 16 + (lane >> 4) * 4 + r;
          atomicAdd(&red[lr][0], p0);
          atomicAdd(&red[lr][1], p1);
        }
      }
    }
    __syncthreads();
    if (tid < 256) {
      int gr = m0 + (tid >> 1);
      if (gr < M) out[(size_t)gr * 2 + (tid & 1)] = red[tid >> 1][tid & 1] + b_o2[tid & 1];
    }
  } else {
#pragma unroll
    for (int fm = 0; fm < 4; fm++) {
#pragma unroll
      for (int fn = 0; fn < 3; fn++) {
        int gc = wn * 48 + fn * 16 + (lane & 15);
        float b = bias[gc];
#pragma unroll
        for (int r = 0; r < 4; r++) {
          int gr = m0 + wm * 64 + fm * 16 + (lane >> 4) * 4 + r;
          if (gr < M) {
            float v = acc[fm][fn][r] + b;
            if (RELU) v = LRELU(v);
            C[(size_t)gr * 192 + gc] = (f16)v;
          }
        }
      }
    }
  }
}

// ---------------- gather-based per-(dst,rel) mean aggregation v5 (bucket + int4 loads) ----------------
__global__ __launch_bounds__(256) void agg_kernel(
    const f16* __restrict__ x, const int* __restrict__ bucket,
    const int* __restrict__ cursor,
    f16* __restrict__ agg0, f16* __restrict__ agg1, int N)
{
  int w = (blockIdx.x << 2) + (threadIdx.x >> 6);
  if (w >= N) return;
  const int lane = threadIdx.x & 63;
  const int g = lane >> 4, sub = lane & 15;
  int deg = cursor[w];
  if (deg > BCAP) deg = BCAP;
  const int4* bk4 = reinterpret_cast<const int4*>(bucket + (size_t)w * BCAP);
  f16x4 a0[3] = {}, a1[3] = {};
  float c1f = 0.f;
  int nj = (deg + 15) >> 4;
  for (int j = 0; j < nj; ++j) {
    int4 ee = bk4[j * 4 + g];
#pragma unroll
    for (int i = 0; i < 4; ++i) {
      int idx = j * 16 + g * 4 + i;
      if (idx < deg) {
        int e = (i == 0) ? ee.x : (i == 1) ? ee.y : (i == 2) ? ee.z : ee.w;
        int src = e & 0x7fffffff;
        const f16* rowp = x + (size_t)src * 192 + sub * 4;
        f16x4 v0 = *reinterpret_cast<const f16x4*>(rowp);
        f16x4 v1 = *reinterpret_cast<const f16x4*>(rowp + 64);
        f16x4 v2 = *reinterpret_cast<const f16x4*>(rowp + 128);
        if (e < 0) {
          c1f += 1.f;
          a1[0] += v0; a1[1] += v1; a1[2] += v2;
        } else {
          a0[0] += v0; a0[1] += v1; a0[2] += v2;
        }
      }
    }
  }
#pragma unroll
  for (int c = 0; c < 3; ++c) {
    a0[c] += shflx4(a0[c], 16); a0[c] += shflx4(a0[c], 32);
    a1[c] += shflx4(a1[c], 16); a1[c] += shflx4(a1[c], 32);
  }
  c1f += __shfl_xor(c1f, 16); c1f += __shfl_xor(c1f, 32);
  if (g == 0) {
    float c0f = (float)deg - c1f;
    float i0 = 1.f / fmaxf(c0f, 1.f);
    float i1 = 1.f / fmaxf(c1f, 1.f);
#pragma unroll
    for (int c = 0; c < 3; ++c) {
      f16x4 o0, o1;
#pragma unroll
      for (int k = 0; k < 4; ++k) {
        o0[k] = (f16)((float)a0[c][k] * i0);
        o1[k] = (f16)((float)a1[c][k] * i1);
      }
      *reinterpret_cast<f16x4*>(agg0 + (size_t)w * 192 + c * 64 + sub * 4) = o0;
      *reinterpret_cast<f16x4*>(agg1 + (size_t)w * 192 + c * 64 + sub * 4) = o1;
    }
  }
}

extern "C" void kernel_launch(void* const* d_in, const int* in_sizes, int n_in,
                              void* d_out, int out_size, void* d_ws, size_t ws_size,
                              hipStream_t stream)
{
  const float* des      = (const float*)d_in[0];
  const float* num_prop = (const float*)d_in[2];
  const float* cat_prop = (const float*)d_in[3];
  const int* edge_index = (const int*)d_in[4];
  const int* edge_type  = (const int*)d_in[5];
  const float* W_des = (const float*)d_in[6];
  const float* b_des = (const float*)d_in[7];
  const float* W_num = (const float*)d_in[8];
  const float* b_num = (const float*)d_in[9];
  const float* W_cat = (const float*)d_in[10];
  const float* b_cat = (const float*)d_in[11];
  const float* W_in  = (const float*)d_in[12];
  const float* b_in  = (const float*)d_in[13];
  const float* W_root= (const float*)d_in[14];
  const float* W_rel = (const float*)d_in[15];
  const float* b_rgcn= (const float*)d_in[16];
  const float* W_o1  = (const float*)d_in[17];
  const float* b_o1  = (const float*)d_in[18];
  const float* W_o2  = (const float*)d_in[19];
  const float* b_o2  = (const float*)d_in[20];
  float* out = (float*)d_out;

  const int N = in_sizes[2] / 4;
  const int E = in_sizes[5];
  (void)n_in; (void)out_size; (void)ws_size;

  const int NB = (N + 255) >> 8;
  const int NBLK = (E + TILE - 1) / TILE;

  char* base = (char*)d_ws;
  size_t off = 0;
  auto take = [&](size_t bytes) -> void* {
    void* p = base + off;
    off += (bytes + 255) & ~(size_t)255;
    return p;
  };
  f16* xA      = (f16*)take((size_t)N * 192 * 2);
  f16* xB      = (f16*)take((size_t)N * 192 * 2);
  f16* agg0    = (f16*)take((size_t)N * 192 * 2);
  f16* agg1    = (f16*)take((size_t)N * 192 * 2);
  int* sorted  = (int*)take((size_t)E * 4);
  int* bucket  = (int*)take((size_t)N * BCAP * 4);
  int* cursor  = (int*)take((size_t)N * 4);
  int* hist    = (int*)take((size_t)NBLK * NB * 4);
  int* binbase = (int*)take((size_t)(NB + 2) * 4);
  f16* WtDes   = (f16*)take(64 * 768 * 2);
  f16* WtIn    = (f16*)take(192 * 192 * 2);
  f16* WtR     = (f16*)take(192 * 576 * 2);
  f16* WtO1    = (f16*)take(192 * 192 * 2);

  const int nbf = (N + 3) / 4;
  const int nsetup = nbf + 192 + 144 + 432 + 144 + NBLK;
  setup_kernel<<<nsetup, 256, 0, stream>>>(
      num_prop, cat_prop, W_num, b_num, W_cat, b_cat,
      W_des, W_in, W_root, W_rel, W_o1,
      xA, WtDes, WtIn, WtR, WtO1,
      edge_index, hist, N, nbf, E, NB);
  scan_kernel<<<1, 512, 0, stream>>>(hist, binbase, NB, NBLK);
  const int nbDES = (N + 127) / 128;
  scatterdes_kernel<<<nbDES + NBLK, 256, 0, stream>>>(
      des, WtDes, b_des, xA, N, edge_index, edge_type, hist, sorted, E, NB, nbDES);
  const int nbX = (N + 127) / 128;
  // W_in GEMM + bucket build (BCAP format) as tail blocks
  gemm_x_kernel<1, true, false, true><<<nbX + NB, 512, 0, stream>>>(
      xA, xA, xA, WtIn, b_in, xB, N, nullptr, nullptr, nullptr,
      sorted, binbase, bucket, cursor, nbX);
  // rgcn 1
  agg_kernel<<<(N + 3) / 4, 256, 0, stream>>>(xB, bucket, cursor, agg0, agg1, N);
  gemm_x_kernel<3, false, false, false><<<nbX, 512, 0, stream>>>(
      xB, agg0, agg1, WtR, b_rgcn, xA, N, nullptr, nullptr, nullptr,
      nullptr, nullptr, nullptr, nullptr, nbX);
  // rgcn 2
  agg_kernel<<<(N + 3) / 4, 256, 0, stream>>>(xA, bucket, cursor, agg0, agg1, N);
  gemm_x_kernel<3, false, false, false><<<nbX, 512, 0, stream>>>(
      xA, agg0, agg1, WtR, b_rgcn, xB, N, nullptr, nullptr, nullptr,
      nullptr, nullptr, nullptr, nullptr, nbX);
  // out = LReLU(x @ W_o1 + b_o1) @ W_o2 + b_o2  (fused)
  gemm_x_kernel<1, false, true, false><<<nbX, 512, 0, stream>>>(
      xB, xB, xB, WtO1, b_o1, nullptr, N, W_o2, b_o2, out,
      nullptr, nullptr, nullptr, nullptr, nbX);
}